// Round 1
// baseline (13634.010 us; speedup 1.0000x reference)
//
#include <hip/hip_runtime.h>
#include <cmath>

#define B_ 16
#define T_ 512
#define E_ 1024
#define H_ 512
#define V_ 10000
#define L_ 64
#define A_ 256
#define CC_ 10
#define K_ 101
#define H4_ 2048

__device__ __forceinline__ float sigm(float x) { return 1.f / (1.f + expf(-x)); }

// ---------------- P0: init persistent state buffers ----------------
__global__ __launch_bounds__(256) void p0_init(float* alpha, float* s, float* g,
                                               float* c0, float* swse,
                                               const float* __restrict__ b_att) {
    int i = blockIdx.x * 256 + threadIdx.x;
    if (i < B_ * T_) alpha[i] = 0.f;
    if (i < B_ * H_) { s[i] = 0.f; c0[i] = 0.f; }
    if (i < B_ * E_) g[i] = 0.f;
    if (i < B_ * A_) swse[i] = b_att[i & (A_ - 1)];
}

// ---------------- P1: enc_proj = hbatch @ W_he  (8192x256, K=1024) ----------------
__global__ __launch_bounds__(256) void p1_encproj(const float* __restrict__ hb,
                                                  const float* __restrict__ W_he,
                                                  float* __restrict__ ep) {
    __shared__ float As[16][68];  // [k][m], padded
    __shared__ float Bs[16][68];  // [k][n], padded
    const int tid = threadIdx.x;
    const int row0 = blockIdx.x * 64;
    const int n0 = blockIdx.y * 64;
    const int tn = tid & 15, tm = tid >> 4;
    float acc[4][4] = {};
    for (int k0 = 0; k0 < E_; k0 += 16) {
        {   // stage A: 64 rows x 16 k
            int m = tid >> 2, kq = (tid & 3) * 4;
            float4 v = *(const float4*)(hb + (size_t)(row0 + m) * E_ + k0 + kq);
            As[kq + 0][m] = v.x; As[kq + 1][m] = v.y;
            As[kq + 2][m] = v.z; As[kq + 3][m] = v.w;
        }
        {   // stage B: 16 k x 64 n
            int kk = tid & 15, nq = (tid >> 4) * 4;
            float4 v = *(const float4*)(W_he + (size_t)(k0 + kk) * A_ + n0 + nq);
            *(float4*)&Bs[kk][nq] = v;
        }
        __syncthreads();
        #pragma unroll
        for (int kk = 0; kk < 16; ++kk) {
            float4 av = *(const float4*)&As[kk][tm * 4];
            float4 bv = *(const float4*)&Bs[kk][tn * 4];
            acc[0][0] += av.x * bv.x; acc[0][1] += av.x * bv.y; acc[0][2] += av.x * bv.z; acc[0][3] += av.x * bv.w;
            acc[1][0] += av.y * bv.x; acc[1][1] += av.y * bv.y; acc[1][2] += av.y * bv.z; acc[1][3] += av.y * bv.w;
            acc[2][0] += av.z * bv.x; acc[2][1] += av.z * bv.y; acc[2][2] += av.z * bv.z; acc[2][3] += av.z * bv.w;
            acc[3][0] += av.w * bv.x; acc[3][1] += av.w * bv.y; acc[3][2] += av.w * bv.z; acc[3][3] += av.w * bv.w;
        }
        __syncthreads();
    }
    #pragma unroll
    for (int i = 0; i < 4; ++i) {
        float4 o = make_float4(acc[i][0], acc[i][1], acc[i][2], acc[i][3]);
        *(float4*)(ep + (size_t)(row0 + tm * 4 + i) * A_ + n0 + tn * 4) = o;
    }
}

// ---------------- K1: location conv + attention scores e ----------------
__global__ __launch_bounds__(256) void k1_scores(const float* __restrict__ swse_g,
                                                 const float* __restrict__ alpha,
                                                 float* __restrict__ e_out,
                                                 const float* __restrict__ enc_proj,
                                                 const float* __restrict__ w_att,
                                                 const float* __restrict__ F_conv,
                                                 const float* __restrict__ W_fe,
                                                 const int* __restrict__ lengths) {
    const int tt = blockIdx.x, b = blockIdx.y, tid = threadIdx.x;
    const int t0 = tt * 32;
    __shared__ float wfe[CC_ * A_];
    __shared__ float watt[A_];
    __shared__ float swse[A_];
    __shared__ float ash[132];
    __shared__ float conv[CC_][32];
    for (int i = tid; i < CC_ * A_; i += 256) wfe[i] = W_fe[i];
    if (tid < A_) { watt[tid] = w_att[tid]; swse[tid] = swse_g[b * A_ + tid]; }
    if (tid < 132) {
        int t = t0 - 50 + tid;
        ash[tid] = (t >= 0 && t < T_) ? alpha[b * T_ + t] : 0.f;
    }
    __syncthreads();
    {   // conv: 10 channels x 32 positions
        int t = tid & 31, cb = tid >> 5;
        for (int c = cb; c < CC_; c += 8) {
            const float* Fc = F_conv + c * K_;
            float acc = 0.f;
            #pragma unroll 4
            for (int k = 0; k < K_; ++k) acc += ash[t + k] * Fc[k];
            conv[c][t] = acc;
        }
    }
    __syncthreads();
    const int wv = tid >> 6, lane = tid & 63;
    const int len = lengths[b];
    for (int i = 0; i < 8; ++i) {
        int tl = wv * 8 + i, t = t0 + tl;
        float cv[CC_];
        #pragma unroll
        for (int c = 0; c < CC_; ++c) cv[c] = conv[c][tl];
        const float* ep = enc_proj + ((size_t)(b * T_ + t)) * A_;
        float v = 0.f;
        #pragma unroll
        for (int j = 0; j < 4; ++j) {
            int a = lane + j * 64;
            float z = ep[a] + swse[a];
            #pragma unroll
            for (int c = 0; c < CC_; ++c) z += cv[c] * wfe[c * A_ + a];
            v += tanhf(z) * watt[a];
        }
        #pragma unroll
        for (int off = 32; off; off >>= 1) v += __shfl_xor(v, off);
        if (lane == 0) e_out[b * T_ + t] = (t < len) ? v : -1e30f;
    }
}

// ---------------- K3: softmax (writes alpha for next step) + context g ----------------
__global__ __launch_bounds__(256) void k3_softmax_g(const float* __restrict__ e_in,
                                                    float* __restrict__ alpha,
                                                    const float* __restrict__ hbatch,
                                                    float* __restrict__ g) {
    const int tt = blockIdx.x, b = blockIdx.y, tid = threadIdx.x;
    __shared__ float red[8];
    __shared__ float a_sh[32];
    float e0 = e_in[b * T_ + tid];
    float e1 = e_in[b * T_ + 256 + tid];
    float m = fmaxf(e0, e1);
    #pragma unroll
    for (int off = 32; off; off >>= 1) m = fmaxf(m, __shfl_xor(m, off));
    if ((tid & 63) == 0) red[tid >> 6] = m;
    __syncthreads();
    m = fmaxf(fmaxf(red[0], red[1]), fmaxf(red[2], red[3]));
    float z = expf(e0 - m) + expf(e1 - m);
    #pragma unroll
    for (int off = 32; off; off >>= 1) z += __shfl_xor(z, off);
    if ((tid & 63) == 0) red[4 + (tid >> 6)] = z;
    __syncthreads();
    z = (red[4] + red[5]) + (red[6] + red[7]);
    float invz = 1.f / z;
    if (tt == 0) {  // one block per b writes the full alpha for the next step
        alpha[b * T_ + tid] = expf(e0 - m) * invz;
        alpha[b * T_ + 256 + tid] = expf(e1 - m) * invz;
    }
    if (tid < 32) a_sh[tid] = expf(e_in[b * T_ + tt * 32 + tid] - m) * invz;
    __syncthreads();
    float4 acc = make_float4(0.f, 0.f, 0.f, 0.f);
    const float4* hb = (const float4*)(hbatch + ((size_t)(b * T_ + tt * 32)) * E_);
    #pragma unroll 4
    for (int j = 0; j < 32; ++j) {
        float av = a_sh[j];
        float4 hv = hb[j * (E_ / 4) + tid];
        acc.x += av * hv.x; acc.y += av * hv.y; acc.z += av * hv.z; acc.w += av * hv.w;
    }
    float* gp = g + b * E_ + tid * 4;
    atomicAdd(gp + 0, acc.x); atomicAdd(gp + 1, acc.y);
    atomicAdd(gp + 2, acc.z); atomicAdd(gp + 3, acc.w);
}

// ---------------- K4a: uv[2560][16] = [g s] @ [W_gy|W_gs ; W_sy|W_ss] ----------------
__global__ __launch_bounds__(256) void k4a_uv(const float* __restrict__ g,
                                              const float* __restrict__ s,
                                              const float* __restrict__ W_gy,
                                              const float* __restrict__ W_sy,
                                              const float* __restrict__ W_gs,
                                              const float* __restrict__ W_ss,
                                              float* __restrict__ uv) {
    const int tid = threadIdx.x;
    const int col_loc = tid & 15, b = tid >> 4;
    const int col = blockIdx.x * 16 + col_loc;
    const float* Wg; const float* Ws; int ld, cw;
    if (blockIdx.x < 32) { Wg = W_gy; Ws = W_sy; ld = H_; cw = col; }
    else                 { Wg = W_gs; Ws = W_ss; ld = H4_; cw = col - H_; }
    float acc = 0.f;
    const float4* g4 = (const float4*)(g + b * E_);
    #pragma unroll 2
    for (int kq = 0; kq < E_ / 4; ++kq) {
        float4 iv = g4[kq];
        int k = kq * 4;
        acc += iv.x * Wg[(size_t)(k + 0) * ld + cw];
        acc += iv.y * Wg[(size_t)(k + 1) * ld + cw];
        acc += iv.z * Wg[(size_t)(k + 2) * ld + cw];
        acc += iv.w * Wg[(size_t)(k + 3) * ld + cw];
    }
    const float4* s4 = (const float4*)(s + b * H_);
    #pragma unroll 2
    for (int kq = 0; kq < H_ / 4; ++kq) {
        float4 iv = s4[kq];
        int k = kq * 4;
        acc += iv.x * Ws[(size_t)(k + 0) * ld + cw];
        acc += iv.y * Ws[(size_t)(k + 1) * ld + cw];
        acc += iv.z * Ws[(size_t)(k + 2) * ld + cw];
        acc += iv.w * Ws[(size_t)(k + 3) * ld + cw];
    }
    uv[col * 16 + b] = acc;
}

// ---------------- K5: y = tanh(u)@W_yy + b_yy  (+ 4 state blocks for step l+1) -------
__global__ __launch_bounds__(256) void k5_y_state(int l,
    const float* __restrict__ uv, const float* __restrict__ b_gy,
    const float* __restrict__ W_yy, const float* __restrict__ b_yy,
    float* __restrict__ out,
    const float* __restrict__ E_ys, const float* __restrict__ b_gs,
    const int* __restrict__ targets,
    const float* __restrict__ c_prev, float* __restrict__ c_cur,
    float* __restrict__ s_glob, float* __restrict__ swse,
    float* __restrict__ g,
    const float* __restrict__ W_se, const float* __restrict__ b_att) {
    __shared__ float lds[2 * 16 * 512];  // 64 KB
    const int tid = threadIdx.x;
    const int bx = blockIdx.x;
    if (bx < V_ / 16) {
        // ---- y GEMM: 16 output cols per block, all 16 batches ----
        float* u_lds = lds;             // [b][h] xor-swizzled
        float* w_lds = lds + 16 * 512;  // [v_loc][h] xor-swizzled
        const int v0 = bx * 16;
        for (int i = tid; i < 8192; i += 256) {
            int h = i >> 4, bb = i & 15;
            int xr = (bb & 7) << 2;
            u_lds[bb * 512 + (h ^ xr)] = tanhf(uv[i] + b_gy[h]);
            w_lds[bb * 512 + (h ^ xr)] = W_yy[(size_t)h * V_ + v0 + bb];
        }
        __syncthreads();
        const int vl = tid & 15, b = tid >> 4;
        const int xu = (b & 7) << 2, xw = (vl & 7) << 2;
        const float* up = u_lds + b * 512;
        const float* wp = w_lds + vl * 512;
        float ax = 0.f, ay = 0.f, az = 0.f, aw = 0.f;
        #pragma unroll 8
        for (int h = 0; h < H_; h += 4) {
            float4 u4 = *(const float4*)(up + (h ^ xu));
            float4 w4 = *(const float4*)(wp + (h ^ xw));
            ax += u4.x * w4.x; ay += u4.y * w4.y;
            az += u4.z * w4.z; aw += u4.w * w4.w;
        }
        float acc = (ax + ay) + (az + aw);
        int v = v0 + vl;
        out[((size_t)b * L_ + l) * V_ + v] = acc + b_yy[v];
    } else {
        // ---- state update for step l+1: LSTM + s@W_se (+b_att) + zero g ----
        float* s_lds = lds;  // [b][h]
        const int aq = bx - V_ / 16;  // 0..3
        for (int j = tid; j < B_ * H_; j += 256) {
            int b = j >> 9, h = j & 511;
            int tgt = targets[b * L_ + l];
            const float* ey = E_ys + (size_t)tgt * H4_;
            float iv = uv[(512 + h) * 16 + b] + ey[h] + b_gs[h];
            float fv = uv[(512 + h + 512) * 16 + b] + ey[h + 512] + b_gs[h + 512];
            float cg = uv[(512 + h + 1024) * 16 + b] + ey[h + 1024] + b_gs[h + 1024];
            float ov = uv[(512 + h + 1536) * 16 + b] + ey[h + 1536] + b_gs[h + 1536];
            float cn = sigm(fv) * c_prev[j] + sigm(iv) * tanhf(cg);
            float sn = sigm(ov) * tanhf(cn);
            s_lds[j] = sn;
            if (aq == 0) { c_cur[j] = cn; s_glob[j] = sn; }
        }
        __syncthreads();
        const int a_loc = tid & 63, bq = tid >> 6;
        const int a = aq * 64 + a_loc;
        float acc0 = b_att[a], acc1 = b_att[a], acc2 = b_att[a], acc3 = b_att[a];
        #pragma unroll 4
        for (int h = 0; h < H_; ++h) {
            float w = W_se[h * A_ + a];
            acc0 += w * s_lds[(bq + 0) * 512 + h];
            acc1 += w * s_lds[(bq + 4) * 512 + h];
            acc2 += w * s_lds[(bq + 8) * 512 + h];
            acc3 += w * s_lds[(bq + 12) * 512 + h];
        }
        swse[(bq + 0) * A_ + a] = acc0;
        swse[(bq + 4) * A_ + a] = acc1;
        swse[(bq + 8) * A_ + a] = acc2;
        swse[(bq + 12) * A_ + a] = acc3;
        if (aq == 0) for (int i = tid; i < B_ * E_; i += 256) g[i] = 0.f;
    }
}

extern "C" void kernel_launch(void* const* d_in, const int* in_sizes, int n_in,
                              void* d_out, int out_size, void* d_ws, size_t ws_size,
                              hipStream_t stream) {
    (void)in_sizes; (void)n_in; (void)out_size; (void)ws_size;
    const float* hbatch = (const float*)d_in[0];
    const int* lengths  = (const int*)d_in[1];
    const int* targets  = (const int*)d_in[2];
    const float* W_sy   = (const float*)d_in[3];
    const float* W_gy   = (const float*)d_in[4];
    const float* b_gy   = (const float*)d_in[5];
    const float* W_yy   = (const float*)d_in[6];
    const float* b_yy   = (const float*)d_in[7];
    const float* E_ys   = (const float*)d_in[8];
    const float* W_ss   = (const float*)d_in[9];
    const float* W_gs   = (const float*)d_in[10];
    const float* b_gs   = (const float*)d_in[11];
    const float* W_se   = (const float*)d_in[12];
    const float* W_he   = (const float*)d_in[13];
    const float* W_fe   = (const float*)d_in[14];
    const float* b_att  = (const float*)d_in[15];
    const float* w_att  = (const float*)d_in[16];
    const float* F_conv = (const float*)d_in[17];
    float* out = (float*)d_out;

    float* ws = (float*)d_ws;
    float* enc_proj = ws;                        // 2,097,152
    float* alpha    = enc_proj + 2097152;        // 8192
    float* e_buf    = alpha + 8192;              // 8192
    float* g        = e_buf + 8192;              // 16384
    float* s        = g + 16384;                 // 8192
    float* c0       = s + 8192;                  // 8192
    float* c1       = c0 + 8192;                 // 8192
    float* swse     = c1 + 8192;                 // 4096
    float* uv       = swse + 4096;               // 40960

    p0_init<<<dim3(64), dim3(256), 0, stream>>>(alpha, s, g, c0, swse, b_att);
    p1_encproj<<<dim3(128, 4), dim3(256), 0, stream>>>(hbatch, W_he, enc_proj);

    for (int l = 0; l < L_; ++l) {
        float* c_prev = (l & 1) ? c1 : c0;
        float* c_cur  = (l & 1) ? c0 : c1;
        k1_scores<<<dim3(16, 16), dim3(256), 0, stream>>>(
            swse, alpha, e_buf, enc_proj, w_att, F_conv, W_fe, lengths);
        k3_softmax_g<<<dim3(16, 16), dim3(256), 0, stream>>>(
            e_buf, alpha, hbatch, g);
        k4a_uv<<<dim3(160), dim3(256), 0, stream>>>(
            g, s, W_gy, W_sy, W_gs, W_ss, uv);
        k5_y_state<<<dim3(V_ / 16 + 4), dim3(256), 0, stream>>>(
            l, uv, b_gy, W_yy, b_yy, out,
            E_ys, b_gs, targets, c_prev, c_cur, s, swse, g, W_se, b_att);
    }
}

// Round 4
// 12107.433 us; speedup vs baseline: 1.1261x; 1.1261x over previous
//
#include <hip/hip_runtime.h>
#include <cmath>

#define B_ 16
#define T_ 512
#define E_ 1024
#define H_ 512
#define V_ 10000
#define L_ 64
#define A_ 256
#define CC_ 10
#define K_ 101
#define H4_ 2048
#define NBLK 256
#define NTHR 256

struct Params {
    const float* hbatch; const int* lengths; const int* targets;
    const float *W_sy, *W_gy, *b_gy, *W_yy, *b_yy, *E_ys, *W_ss, *W_gs, *b_gs;
    const float *W_se, *W_he, *W_fe, *b_att, *w_att, *F_conv;
    float* out;
    float *enc_proj, *alpha, *e, *g, *s, *c0, *c1, *swse, *u_pre, *rec_pre, *u_t;
    int *tilecnt, *bar;
};

__device__ __forceinline__ float fsigm(float x) {
    return 1.f / (1.f + __expf(-x));
}
__device__ __forceinline__ float ftanh(float x) {
    float ax = fabsf(x);
    float ex = __expf(-2.f * ax);
    float t = (1.f - ex) / (1.f + ex);
    return copysignf(t, x);
}

// zero barrier + tile counters before every mega launch (ws is poisoned 0xAA)
__global__ void bar_init(int* tilecnt_and_bar) {
    if (threadIdx.x < 128) tilecnt_and_bar[threadIdx.x] = 0;
}

// software grid barrier: all 256 blocks co-resident (grid == CU count).
// bar[0] = arrive count, bar[32] = generation (separate cachelines).
__device__ __forceinline__ void gsync(int* bar, int target) {
    __syncthreads();
    if (threadIdx.x == 0) {
        int arrived = __hip_atomic_fetch_add(&bar[0], 1, __ATOMIC_ACQ_REL,
                                             __HIP_MEMORY_SCOPE_AGENT);
        if (arrived == NBLK - 1) {
            __hip_atomic_store(&bar[0], 0, __ATOMIC_RELAXED, __HIP_MEMORY_SCOPE_AGENT);
            __hip_atomic_store(&bar[32], target, __ATOMIC_RELEASE, __HIP_MEMORY_SCOPE_AGENT);
        } else {
            int spins = 0;
            while (__hip_atomic_load(&bar[32], __ATOMIC_ACQUIRE,
                                     __HIP_MEMORY_SCOPE_AGENT) < target) {
                __builtin_amdgcn_s_sleep(2);
                if (++spins > (1 << 26)) break;  // failsafe: fail visibly, don't hang
            }
        }
    }
    __syncthreads();
}

__global__ __launch_bounds__(NTHR, 1) void mega(Params p) {
    const int bx = blockIdx.x, tid = threadIdx.x;
    const int lane = tid & 63, wv = tid >> 6;
    __shared__ __align__(16) float s_res[3840];   // wfe 2560 | watt 256 | fconv 1010
    __shared__ __align__(16) float s_scr[10560];  // per-phase scratch
    int bt = 0;

    // ---------- resident LDS ----------
    for (int i = tid; i < CC_ * A_; i += NTHR) s_res[i] = p.W_fe[i];
    if (tid < A_) s_res[2560 + tid] = p.w_att[tid];
    for (int i = tid; i < CC_ * K_; i += NTHR) s_res[2816 + i] = p.F_conv[i];

    // ---------- init persistent state ----------
    if (bx < B_) {
        p.alpha[bx * T_ + tid] = 0.f; p.alpha[bx * T_ + 256 + tid] = 0.f;
        p.s[bx * H_ + tid] = 0.f;     p.s[bx * H_ + 256 + tid] = 0.f;
        p.c0[bx * H_ + tid] = 0.f;    p.c0[bx * H_ + 256 + tid] = 0.f;
        p.swse[bx * A_ + tid] = p.b_att[tid];
    }

    // ---------- enc_proj = hbatch @ W_he (8192x256, K=1024); 2 64x64 tiles/block ----
    {
        float* As = s_scr;          // [16][68]
        float* Bs = s_scr + 1088;   // [16][68]
        for (int tt2 = 0; tt2 < 2; ++tt2) {
            const int tile = bx * 2 + tt2;
            const int row0 = (tile >> 2) * 64, n0 = (tile & 3) * 64;
            const int tn = tid & 15, tm = tid >> 4;
            float acc[4][4] = {};
            for (int k0 = 0; k0 < E_; k0 += 16) {
                __syncthreads();
                {
                    int m = tid >> 2, kq = (tid & 3) * 4;
                    float4 v = *(const float4*)(p.hbatch + (size_t)(row0 + m) * E_ + k0 + kq);
                    As[(kq + 0) * 68 + m] = v.x; As[(kq + 1) * 68 + m] = v.y;
                    As[(kq + 2) * 68 + m] = v.z; As[(kq + 3) * 68 + m] = v.w;
                }
                {
                    int kk = tid & 15, nq = (tid >> 4) * 4;
                    float4 v = *(const float4*)(p.W_he + (size_t)(k0 + kk) * A_ + n0 + nq);
                    *(float4*)&Bs[kk * 68 + nq] = v;
                }
                __syncthreads();
                #pragma unroll
                for (int kk = 0; kk < 16; ++kk) {
                    float4 av = *(const float4*)&As[kk * 68 + tm * 4];
                    float4 bv = *(const float4*)&Bs[kk * 68 + tn * 4];
                    acc[0][0] += av.x * bv.x; acc[0][1] += av.x * bv.y; acc[0][2] += av.x * bv.z; acc[0][3] += av.x * bv.w;
                    acc[1][0] += av.y * bv.x; acc[1][1] += av.y * bv.y; acc[1][2] += av.y * bv.z; acc[1][3] += av.y * bv.w;
                    acc[2][0] += av.z * bv.x; acc[2][1] += av.z * bv.y; acc[2][2] += av.z * bv.z; acc[2][3] += av.z * bv.w;
                    acc[3][0] += av.w * bv.x; acc[3][1] += av.w * bv.y; acc[3][2] += av.w * bv.z; acc[3][3] += av.w * bv.w;
                }
            }
            #pragma unroll
            for (int i = 0; i < 4; ++i) {
                float4 o = make_float4(acc[i][0], acc[i][1], acc[i][2], acc[i][3]);
                *(float4*)(p.enc_proj + (size_t)(row0 + tm * 4 + i) * A_ + n0 + tn * 4) = o;
            }
        }
    }

    gsync(p.bar, ++bt);

    // ================= 64 decode steps =================
    for (int l = 0; l < L_; ++l) {
        // ---------- P1: attention scores e[b][t] (16 b x 16 t-chunks) ----------
        {
            const int b = bx >> 4, tc = bx & 15, t0 = tc * 32;
            float* ash   = s_scr;          // 132
            float* conv  = s_scr + 132;    // 320
            float* cpart = s_scr + 708;    // [10][8][32]
            if (tid < 132) {
                int t = t0 - 50 + tid;
                ash[tid] = (t >= 0 && t < T_) ? p.alpha[b * T_ + t] : 0.f;
            }
            __syncthreads();
            {
                const int t = tid & 31, kq = tid >> 5;
                const int kbeg = kq * 13, kend = (kbeg + 13 < K_) ? kbeg + 13 : K_;
                float accc[CC_] = {};
                for (int k = kbeg; k < kend; ++k) {
                    float av = ash[t + k];
                    #pragma unroll
                    for (int c = 0; c < CC_; ++c) accc[c] += av * s_res[2816 + c * K_ + k];
                }
                #pragma unroll
                for (int c = 0; c < CC_; ++c) cpart[(c * 8 + kq) * 32 + t] = accc[c];
            }
            __syncthreads();
            for (int i = tid; i < CC_ * 32; i += NTHR) {
                int c = i >> 5, t = i & 31;
                float sv = 0.f;
                #pragma unroll
                for (int q = 0; q < 8; ++q) sv += cpart[(c * 8 + q) * 32 + t];
                conv[c * 32 + t] = sv;
            }
            __syncthreads();
            float wfeR[4][CC_], swl4[4], watt4[4];
            #pragma unroll
            for (int j = 0; j < 4; ++j) {
                int a = lane + j * 64;
                swl4[j] = p.swse[b * A_ + a];
                watt4[j] = s_res[2560 + a];
                #pragma unroll
                for (int c = 0; c < CC_; ++c) wfeR[j][c] = s_res[c * A_ + a];
            }
            const int len = p.lengths[b];
            for (int i = 0; i < 8; ++i) {
                int tl = wv * 8 + i, t = t0 + tl;
                float cvv[CC_];
                #pragma unroll
                for (int c = 0; c < CC_; ++c) cvv[c] = conv[c * 32 + tl];
                const float* ep = p.enc_proj + (size_t)(b * T_ + t) * A_;
                float v = 0.f;
                #pragma unroll
                for (int j = 0; j < 4; ++j) {
                    int a = lane + j * 64;
                    float z = ep[a] + swl4[j];
                    #pragma unroll
                    for (int c = 0; c < CC_; ++c) z += cvv[c] * wfeR[j][c];
                    v += ftanh(z) * watt4[j];
                }
                #pragma unroll
                for (int off = 32; off; off >>= 1) v += __shfl_xor(v, off);
                if (lane == 0) p.e[b * T_ + t] = (t < len) ? v : -1e30f;
            }
        }
        gsync(p.bar, ++bt);

        // ---------- P2: softmax + context g (16 b x 16 e-chunks) + zero pre-bufs ----
        {
            const int b = bx >> 4, ec = bx & 15;
            float* a_sh = s_scr;         // 512
            float* red  = s_scr + 512;   // 16
            float* pg   = s_scr + 528;   // 1024
            float v0 = p.e[b * T_ + tid], v1 = p.e[b * T_ + 256 + tid];
            float m = fmaxf(v0, v1);
            #pragma unroll
            for (int off = 32; off; off >>= 1) m = fmaxf(m, __shfl_xor(m, off));
            if ((tid & 63) == 0) red[tid >> 6] = m;
            __syncthreads();
            m = fmaxf(fmaxf(red[0], red[1]), fmaxf(red[2], red[3]));
            float z0 = __expf(v0 - m), z1 = __expf(v1 - m);
            float z = z0 + z1;
            #pragma unroll
            for (int off = 32; off; off >>= 1) z += __shfl_xor(z, off);
            if ((tid & 63) == 0) red[8 + (tid >> 6)] = z;
            __syncthreads();
            z = (red[8] + red[9]) + (red[10] + red[11]);
            float invz = 1.f / z;
            float a0 = z0 * invz, a1 = z1 * invz;
            a_sh[tid] = a0; a_sh[256 + tid] = a1;
            if (ec == 0) {  // one chunk per b writes next-step alpha
                p.alpha[b * T_ + tid] = a0; p.alpha[b * T_ + 256 + tid] = a1;
            }
            __syncthreads();
            const int e4 = tid & 15, tq = tid >> 4;
            float4 acc = make_float4(0.f, 0.f, 0.f, 0.f);
            const float* hb = p.hbatch + (size_t)(b * T_ + tq * 32) * E_ + ec * 64 + e4 * 4;
            #pragma unroll 4
            for (int tt = 0; tt < 32; ++tt) {
                float av = a_sh[tq * 32 + tt];
                float4 hv = *(const float4*)(hb + (size_t)tt * E_);
                acc.x += av * hv.x; acc.y += av * hv.y;
                acc.z += av * hv.z; acc.w += av * hv.w;
            }
            *(float4*)(pg + tid * 4) = acc;
            __syncthreads();
            if (tid < 64) {
                float sv = 0.f;
                #pragma unroll
                for (int q = 0; q < 16; ++q) sv += pg[(q * 16 + (tid >> 2)) * 4 + (tid & 3)];
                p.g[b * E_ + ec * 64 + tid] = sv;
            }
            // zero u_pre (8192) + rec_pre (32768) (contiguous) and tile counters
            int idx = bx * NTHR + tid;
            if (idx < 8192) p.u_pre[idx] = 0.f;
            else if (idx < 40960) p.rec_pre[idx - 8192] = 0.f;
            if (bx == NBLK - 1 && tid < 8) p.tilecnt[tid] = 0;
        }
        gsync(p.bar, ++bt);

        // ---------- P4: [u|rec] partial GEMM, 40 c-tiles x 6 k-chunks ----------
        if (bx < 240) {
            const int ct = bx / 6, kc = bx % 6;
            const int c0 = ct * 64, k0 = kc * 256;
            float* xs = s_scr;  // [16][256] x-slice ([g|s])
            for (int i = tid; i < 1024; i += NTHR) {
                int b = i >> 6, off = (i & 63) * 4;
                const float* src = (k0 < E_) ? (p.g + (size_t)b * E_ + k0 + off)
                                             : (p.s + (size_t)b * H_ + (k0 - E_) + off);
                *(float4*)&xs[b * 256 + off] = *(const float4*)src;
            }
            __syncthreads();
            const float* Wb; int ld, cc;
            if (ct < 8) {
                ld = H_; cc = c0 + lane;
                Wb = (k0 < E_) ? (p.W_gy + (size_t)k0 * H_) : (p.W_sy + (size_t)(k0 - E_) * H_);
            } else {
                ld = H4_; cc = c0 - 512 + lane;
                Wb = (k0 < E_) ? (p.W_gs + (size_t)k0 * H4_) : (p.W_ss + (size_t)(k0 - E_) * H4_);
            }
            Wb += cc;
            const int b0 = wv * 4;
            const float* x0 = xs + (b0 + 0) * 256;
            const float* x1 = xs + (b0 + 1) * 256;
            const float* x2 = xs + (b0 + 2) * 256;
            const float* x3 = xs + (b0 + 3) * 256;
            float a0 = 0.f, a1 = 0.f, a2 = 0.f, a3 = 0.f;
            #pragma unroll 4
            for (int k = 0; k < 256; k += 4) {
                float w0 = Wb[(size_t)(k + 0) * ld];
                float w1 = Wb[(size_t)(k + 1) * ld];
                float w2 = Wb[(size_t)(k + 2) * ld];
                float w3 = Wb[(size_t)(k + 3) * ld];
                float4 v0 = *(const float4*)(x0 + k);
                float4 v1 = *(const float4*)(x1 + k);
                float4 v2 = *(const float4*)(x2 + k);
                float4 v3 = *(const float4*)(x3 + k);
                a0 += w0 * v0.x + w1 * v0.y + w2 * v0.z + w3 * v0.w;
                a1 += w0 * v1.x + w1 * v1.y + w2 * v1.z + w3 * v1.w;
                a2 += w0 * v2.x + w1 * v2.y + w2 * v2.z + w3 * v2.w;
                a3 += w0 * v3.x + w1 * v3.y + w2 * v3.z + w3 * v3.w;
            }
            if (ct < 8) {
                atomicAdd(p.u_pre + (size_t)(b0 + 0) * H_ + cc, a0);
                atomicAdd(p.u_pre + (size_t)(b0 + 1) * H_ + cc, a1);
                atomicAdd(p.u_pre + (size_t)(b0 + 2) * H_ + cc, a2);
                atomicAdd(p.u_pre + (size_t)(b0 + 3) * H_ + cc, a3);
                __threadfence();
                __syncthreads();
                int* lflag = (int*)&s_scr[4096];
                if (tid == 0) {
                    int done = __hip_atomic_fetch_add(&p.tilecnt[ct], 1, __ATOMIC_ACQ_REL,
                                                      __HIP_MEMORY_SCOPE_AGENT);
                    lflag[0] = (done == 5) ? 1 : 0;
                }
                __syncthreads();
                if (lflag[0]) {  // last k-chunk for this tile: finalize u_t = tanh(u+b)
                    #pragma unroll
                    for (int bi = 0; bi < 4; ++bi) {
                        int b = b0 + bi;
                        float v = __hip_atomic_load(p.u_pre + (size_t)b * H_ + cc,
                                                    __ATOMIC_RELAXED, __HIP_MEMORY_SCOPE_AGENT);
                        p.u_t[(size_t)b * H_ + cc] = ftanh(v + p.b_gy[cc]);
                    }
                }
            } else {
                atomicAdd(p.rec_pre + (size_t)(b0 + 0) * H4_ + cc, a0);
                atomicAdd(p.rec_pre + (size_t)(b0 + 1) * H4_ + cc, a1);
                atomicAdd(p.rec_pre + (size_t)(b0 + 2) * H4_ + cc, a2);
                atomicAdd(p.rec_pre + (size_t)(b0 + 3) * H4_ + cc, a3);
            }
        }
        gsync(p.bar, ++bt);

        // ---------- P5: y-GEMM (0..156) | LSTM + swse (157..220) ----------
        if (bx < 157) {
            float* u_sh = s_scr;  // 8192 = u_t staged
            for (int i = tid; i < 2048; i += NTHR)
                ((float4*)u_sh)[i] = ((const float4*)p.u_t)[i];
            __syncthreads();
            const int v = bx * 64 + lane;
            const int vc = (v < V_) ? v : V_ - 1;
            const int b0 = wv * 4;
            float acc[4] = {0.f, 0.f, 0.f, 0.f};
            #pragma unroll 2
            for (int k0 = 0; k0 < H_; k0 += 8) {
                float w[8];
                #pragma unroll
                for (int kk = 0; kk < 8; ++kk)
                    w[kk] = p.W_yy[(size_t)(k0 + kk) * V_ + vc];
                #pragma unroll
                for (int bi = 0; bi < 4; ++bi) {
                    const float* ub = u_sh + (b0 + bi) * H_ + k0;
                    float4 ua = *(const float4*)ub;
                    float4 ub4 = *(const float4*)(ub + 4);
                    acc[bi] += ua.x * w[0] + ua.y * w[1] + ua.z * w[2] + ua.w * w[3]
                             + ub4.x * w[4] + ub4.y * w[5] + ub4.z * w[6] + ub4.w * w[7];
                }
            }
            if (v < V_) {
                float by = p.b_yy[v];
                #pragma unroll
                for (int bi = 0; bi < 4; ++bi)
                    p.out[((size_t)(b0 + bi) * L_ + l) * V_ + v] = acc[bi] + by;
            }
        } else if (bx < 221) {
            const int j2 = bx - 157, b = j2 & 15, q = j2 >> 4;
            float* s_sh = s_scr;         // 512
            float* pr   = s_scr + 512;   // 256
            const int tgt = p.targets[b * L_ + l];
            const float* ey = p.E_ys + (size_t)tgt * H4_;
            const float* rc = p.rec_pre + (size_t)b * H4_;
            const float* cprev = ((l & 1) ? p.c1 : p.c0) + b * H_;
            float* ccur = ((l & 1) ? p.c0 : p.c1) + b * H_;
            for (int h = tid; h < H_; h += NTHR) {
                float iv  = rc[h]        + ey[h]        + p.b_gs[h];
                float fv  = rc[512 + h]  + ey[512 + h]  + p.b_gs[512 + h];
                float cg2 = rc[1024 + h] + ey[1024 + h] + p.b_gs[1024 + h];
                float ov  = rc[1536 + h] + ey[1536 + h] + p.b_gs[1536 + h];
                float cn = fsigm(fv) * cprev[h] + fsigm(iv) * ftanh(cg2);
                float sn = fsigm(ov) * ftanh(cn);
                s_sh[h] = sn;
                if (q == 0) { ccur[h] = cn; p.s[b * H_ + h] = sn; }
            }
            __syncthreads();
            const int al = tid & 63, hq = tid >> 6;
            const int a = q * 64 + al;
            float fa = 0.f;
            #pragma unroll 4
            for (int hh = 0; hh < 128; ++hh) {
                int h = hq * 128 + hh;
                fa += s_sh[h] * p.W_se[(size_t)h * A_ + a];
            }
            pr[hq * 64 + al] = fa;
            __syncthreads();
            if (tid < 64) {
                float sv = pr[tid] + pr[64 + tid] + pr[128 + tid] + pr[192 + tid]
                         + p.b_att[q * 64 + tid];
                p.swse[b * A_ + q * 64 + tid] = sv;
            }
        }
        gsync(p.bar, ++bt);
    }
}

extern "C" void kernel_launch(void* const* d_in, const int* in_sizes, int n_in,
                              void* d_out, int out_size, void* d_ws, size_t ws_size,
                              hipStream_t stream) {
    (void)in_sizes; (void)n_in; (void)out_size; (void)ws_size;
    Params p;
    p.hbatch = (const float*)d_in[0];
    p.lengths = (const int*)d_in[1];
    p.targets = (const int*)d_in[2];
    p.W_sy  = (const float*)d_in[3];
    p.W_gy  = (const float*)d_in[4];
    p.b_gy  = (const float*)d_in[5];
    p.W_yy  = (const float*)d_in[6];
    p.b_yy  = (const float*)d_in[7];
    p.E_ys  = (const float*)d_in[8];
    p.W_ss  = (const float*)d_in[9];
    p.W_gs  = (const float*)d_in[10];
    p.b_gs  = (const float*)d_in[11];
    p.W_se  = (const float*)d_in[12];
    p.W_he  = (const float*)d_in[13];
    p.W_fe  = (const float*)d_in[14];
    p.b_att = (const float*)d_in[15];
    p.w_att = (const float*)d_in[16];
    p.F_conv = (const float*)d_in[17];
    p.out = (float*)d_out;

    float* ws = (float*)d_ws;
    p.enc_proj = ws;                    // 2,097,152
    p.alpha    = ws + 2097152;          // 8192
    p.e        = ws + 2105344;          // 8192
    p.g        = ws + 2113536;          // 16384
    p.s        = ws + 2129920;          // 8192
    p.c0       = ws + 2138112;          // 8192
    p.c1       = ws + 2146304;          // 8192
    p.swse     = ws + 2154496;          // 4096
    p.u_pre    = ws + 2158592;          // 8192
    p.rec_pre  = ws + 2166784;          // 32768 (contiguous after u_pre)
    p.u_t      = ws + 2199552;          // 8192
    p.tilecnt  = (int*)(ws + 2207744);  // 64 ints
    p.bar      = (int*)(ws + 2207808);  // 64 ints
    // total ~8.83 MB — same footprint class as the round-1 layout that passed

    bar_init<<<dim3(1), dim3(128), 0, stream>>>(p.tilecnt);  // zeros tilecnt+bar (contiguous)
    mega<<<dim3(NBLK), dim3(NTHR), 0, stream>>>(p);
}